// Round 3
// baseline (69.581 us; speedup 1.0000x reference)
//
#include <hip/hip_runtime.h>
#include <math.h>

// QuantumLayer B=512, Q=14. State 2^14 fp32 in registers: 32/thread x 512 threads.
//
// m = state index, bit 13 = wire 0 (MSB).
// Phase A: local r = m[13:9] (32 regs), tid = m[8:0].
//   -> RY passes wires 0..4 (bits 13..9) register-local.
// LDS transpose (chunk stride 36 floats: writes 2-way/bank = free, reads b128 clean) to
// Phase B: local u = m[8:4], tid' = (m[13:9]<<4) | m[3:0].
//   -> wires 5..9 register-local; wires 10..13 = lane bits 3..0 via shfl_xor 8/4/2/1.
// Fill: RY(x)+RY(w0) merged (adjacent same-wire RYs compose), pushed through CNOT
//   chain #1 as g = m ^ (m>>1); built as a product tree (~60 mults/thread).
// Measurement: CNOT chain #2 folded as prefix-parity signs; 6 accumulators with
//   compile-time signs; lane/wave-uniform signs are parity(tid >> k).
//
// Per-thread live set ~55 floats -> fits 128 VGPRs (launch_bounds(512,4)),
// 74.4 KB LDS -> 2 blocks/CU, grid 512 = exact 2/CU fit. NO scratch spill.

#define Q 14
#define BLOCK 512
#define SCHUNK 36   // 32 data + 4 pad floats; 144 B chunk, 16B-aligned

template<int BIT>
__device__ __forceinline__ void rpass(float st[32], float c, float s) {
#pragma unroll
    for (int k = 0; k < 16; ++k) {
        const int n0 = ((k >> BIT) << (BIT + 1)) | (k & ((1 << BIT) - 1));
        const int n1 = n0 | (1 << BIT);
        float a = st[n0], b = st[n1];
        st[n0] = c * a - s * b;
        st[n1] = s * a + c * b;
    }
}

__device__ __forceinline__ float psign(int bits, float v) {
    return (__builtin_popcount(bits) & 1) ? -v : v;
}

__global__ __launch_bounds__(BLOCK, 4)
void quantum_kernel(const float* __restrict__ x,   // [B,14]
                    const float* __restrict__ w,   // [2,14]
                    float* __restrict__ out)       // [B,14]
{
    __shared__ float lds[BLOCK * SCHUNK];          // 73728 B
    __shared__ float2 cs0[Q], cs1[Q];
    __shared__ float red[8 * Q];

    const int b = blockIdx.x;
    const int tid = threadIdx.x;
    const int lane = tid & 63;
    const int wv = tid >> 6;

    if (tid < Q) {
        float a0 = 0.5f * (x[b * Q + tid] + w[tid]);   // RY(x)·RY(w0) merged
        cs0[tid] = make_float2(cosf(a0), sinf(a0));
        float a1 = 0.5f * w[Q + tid];
        cs1[tid] = make_float2(cosf(a1), sinf(a1));
    }
    __syncthreads();

    // ---- Fill (phase A). tid = m[8:0], r = m[13:9].
    // wire i uses g bit (13-i), g_b = m_b ^ m_{b+1}.
    // wires 6..13 <-> g bits 7..0: thread-uniform (within tid).
    float H = 1.0f;
#pragma unroll
    for (int j = 0; j <= 7; ++j) {
        int gj = ((tid >> (j + 1)) ^ (tid >> j)) & 1;
        float2 f = cs0[13 - j];
        H *= gj ? f.y : f.x;
    }
    const int t8 = (tid >> 8) & 1;                 // wire5: g8 = t8 ^ r0
    float2 f5 = cs0[5];
    float F5_0 = t8 ? f5.y : f5.x;
    float F5_1 = t8 ? f5.x : f5.y;
    float2 f4 = cs0[4], f3 = cs0[3], f2 = cs0[2], f1 = cs0[1], f0 = cs0[0];

    float st[32];
    {
        float t1[2], t2[4], t3[8], t4[16];
        t1[0] = H * F5_0;  t1[1] = H * F5_1;
#pragma unroll
        for (int r = 0; r < 4; ++r) {              // wire4: g9 = r0^r1
            int g = ((r >> 1) ^ r) & 1;
            t2[r] = t1[r & 1] * (g ? f4.y : f4.x);
        }
#pragma unroll
        for (int r = 0; r < 8; ++r) {              // wire3: g10 = r1^r2
            int g = ((r >> 2) ^ (r >> 1)) & 1;
            t3[r] = t2[r & 3] * (g ? f3.y : f3.x);
        }
#pragma unroll
        for (int r = 0; r < 16; ++r) {             // wire2: g11 = r2^r3
            int g = ((r >> 3) ^ (r >> 2)) & 1;
            t4[r] = t3[r & 7] * (g ? f2.y : f2.x);
        }
        // wire1: g12 = r3^r4; wire0: g13 = r4
        float FF00 = f0.x * f1.x;   // r4=0,r3=0
        float FF01 = f0.x * f1.y;   // r4=0,r3=1
        float FF10 = f0.y * f1.y;   // r4=1,r3=0
        float FF11 = f0.y * f1.x;   // r4=1,r3=1
#pragma unroll
        for (int r = 0; r < 32; ++r) {
            int r4b = (r >> 4) & 1, r3b = (r >> 3) & 1;
            float FFv = r4b ? (r3b ? FF11 : FF10) : (r3b ? FF01 : FF00);
            st[r] = t4[r & 15] * FFv;
        }
    }

    // ---- Phase A passes: wires 0..4 on r bits 4..0
    { float2 cs = cs1[0]; rpass<4>(st, cs.x, cs.y); }
    { float2 cs = cs1[1]; rpass<3>(st, cs.x, cs.y); }
    { float2 cs = cs1[2]; rpass<2>(st, cs.x, cs.y); }
    { float2 cs = cs1[3]; rpass<1>(st, cs.x, cs.y); }
    { float2 cs = cs1[4]; rpass<0>(st, cs.x, cs.y); }

    // ---- Transpose: element r of thread t -> chunk (r<<4)|(t&15), slot t>>4.
    {
        const int base = (tid & 15) * SCHUNK + (tid >> 4);
#pragma unroll
        for (int r = 0; r < 32; ++r)
            lds[base + (r << 4) * SCHUNK] = st[r];
    }
    __syncthreads();
    {
        const int rbase = tid * SCHUNK;            // contiguous -> b128 reads
#pragma unroll
        for (int u = 0; u < 32; ++u) st[u] = lds[rbase + u];
    }
    // now tid = (m[13:9]<<4)|m[3:0], local u = m[8:4]

    // ---- Phase B passes: wires 5..9 on u bits 4..0
    { float2 cs = cs1[5]; rpass<4>(st, cs.x, cs.y); }
    { float2 cs = cs1[6]; rpass<3>(st, cs.x, cs.y); }
    { float2 cs = cs1[7]; rpass<2>(st, cs.x, cs.y); }
    { float2 cs = cs1[8]; rpass<1>(st, cs.x, cs.y); }
    { float2 cs = cs1[9]; rpass<0>(st, cs.x, cs.y); }

    // ---- Wires 10..13: lane bits 3..0, shfl_xor masks 8,4,2,1
    {
        float2 cs = cs1[10];
        float sg = (lane & 8) ? cs.y : -cs.y;
#pragma unroll
        for (int u = 0; u < 32; ++u) {
            float pv = __shfl_xor(st[u], 8, 64);
            st[u] = cs.x * st[u] + sg * pv;
        }
    }
    {
        float2 cs = cs1[11];
        float sg = (lane & 4) ? cs.y : -cs.y;
#pragma unroll
        for (int u = 0; u < 32; ++u) {
            float pv = __shfl_xor(st[u], 4, 64);
            st[u] = cs.x * st[u] + sg * pv;
        }
    }
    {
        float2 cs = cs1[12];
        float sg = (lane & 2) ? cs.y : -cs.y;
#pragma unroll
        for (int u = 0; u < 32; ++u) {
            float pv = __shfl_xor(st[u], 2, 64);   // DPP quad_perm
            st[u] = cs.x * st[u] + sg * pv;
        }
    }
    {
        float2 cs = cs1[13];
        float sg = (lane & 1) ? cs.y : -cs.y;
#pragma unroll
        for (int u = 0; u < 32; ++u) {
            float pv = __shfl_xor(st[u], 1, 64);   // DPP quad_perm
            st[u] = cs.x * st[u] + sg * pv;
        }
    }

    // ---- Measurement: 6 accumulators, compile-time signs on u bits.
    float acc0 = 0.f, acc1 = 0.f, acc2 = 0.f, acc3 = 0.f, acc4 = 0.f, acc5 = 0.f;
#pragma unroll
    for (int u = 0; u < 32; ++u) {
        float p2 = st[u] * st[u];
        acc0 += p2;
        acc1 += (__builtin_popcount(u >> 4) & 1) ? -p2 : p2;
        acc2 += (__builtin_popcount(u >> 3) & 1) ? -p2 : p2;
        acc3 += (__builtin_popcount(u >> 2) & 1) ? -p2 : p2;
        acc4 += (__builtin_popcount(u >> 1) & 1) ? -p2 : p2;
        acc5 += (__builtin_popcount(u) & 1) ? -p2 : p2;
    }

    // tid bits: 8..4 = m[13:9], 3..0 = m[3:0]. out_i sign = parity(m >> (13-i)).
    float v[Q];
    v[0]  = psign(tid >> 8, acc0);
    v[1]  = psign(tid >> 7, acc0);
    v[2]  = psign(tid >> 6, acc0);
    v[3]  = psign(tid >> 5, acc0);
    v[4]  = psign(tid >> 4, acc0);
    float P4 = psign(tid >> 4, 1.0f);
    v[5]  = P4 * acc1;
    v[6]  = P4 * acc2;
    v[7]  = P4 * acc3;
    v[8]  = P4 * acc4;
    v[9]  = P4 * acc5;
    v[10] = psign(tid >> 3, acc5);
    v[11] = psign(tid >> 2, acc5);
    v[12] = psign(tid >> 1, acc5);
    v[13] = psign(tid, acc5);

    // ---- Block reduction: wave shuffle, then 8 wave-partials in LDS.
#pragma unroll
    for (int i = 0; i < Q; ++i) {
        float t = v[i];
        for (int off = 32; off > 0; off >>= 1) t += __shfl_down(t, off, 64);
        v[i] = t;
    }
    if (lane == 0) {
#pragma unroll
        for (int i = 0; i < Q; ++i) red[wv * Q + i] = v[i];
    }
    __syncthreads();
    if (tid < Q) {
        float s = 0.f;
#pragma unroll
        for (int k = 0; k < 8; ++k) s += red[k * Q + tid];
        out[b * Q + tid] = s;
    }
}

extern "C" void kernel_launch(void* const* d_in, const int* in_sizes, int n_in,
                              void* d_out, int out_size, void* d_ws, size_t ws_size,
                              hipStream_t stream) {
    const float* x = (const float*)d_in[0];
    const float* w = (const float*)d_in[1];
    float* out = (float*)d_out;
    const int B = in_sizes[0] / Q;   // 512
    quantum_kernel<<<dim3(B), dim3(BLOCK), 0, stream>>>(x, w, out);
}

// Round 4
// 64.367 us; speedup vs baseline: 1.0810x; 1.0810x over previous
//
#include <hip/hip_runtime.h>
#include <math.h>

// QuantumLayer B=512, Q=14. State 2^14 fp32 in registers: 32/thread x 512 threads.
//
// m = state index, bit 13 = wire 0 (MSB).
// Phase A: local r = m[13:9] (32 regs), tid = m[8:0] -> wires 0..4 register-local.
// LDS transpose (chunk stride 36 floats; scatter writes 2-way/bank = free,
//   reads ds_read_b128) to Phase B: local u = m[8:4], tid' = (m[13:9]<<4)|m[3:0]
//   -> wires 5..9 register-local; wires 10..13 live in lane bits 3..0.
// Cross-lane without the LDS pipe where possible:
//   wire 10 (xor8, within 16-row) = DPP row_ror:8; wire 12/13 (xor2/xor1) = DPP
//   quad_perm 0x4E/0xB1; wire 11 (xor4) = ds_swizzle 0x101F.
// Fill: RY(x)+RY(w0) merged, pushed through CNOT chain #1 (g = m ^ (m>>1)),
//   built as a product tree. Chain #2 folded into measurement as prefix parity.
// Reduction: 11 shared half-wave sums (DPP ror 1/2/4/8 + swizzle xor16); lane-bit
//   signs pre-multiplied, m[13:10] signs become 16 partial groups resolved in LDS.

#define Q 14
#define BLOCK 512
#define SCHUNK 36   // 32 data + 4 pad floats; 144 B chunk, 16B-aligned

template<int CTRL>
__device__ __forceinline__ float dppf(float v) {
    return __int_as_float(__builtin_amdgcn_update_dpp(
        0, __float_as_int(v), CTRL, 0xF, 0xF, true));
}
template<int OFF>
__device__ __forceinline__ float swzf(float v) {
    return __int_as_float(__builtin_amdgcn_ds_swizzle(__float_as_int(v), OFF));
}

// all-reduce sum over a 32-lane half: DPP rotates within 16-rows, then xor16.
__device__ __forceinline__ float sum32(float v) {
    v += dppf<0x121>(v);   // row_ror:1
    v += dppf<0x122>(v);   // row_ror:2
    v += dppf<0x124>(v);   // row_ror:4
    v += dppf<0x128>(v);   // row_ror:8
    v += swzf<0x401F>(v);  // xor16
    return v;
}

template<int BIT>
__device__ __forceinline__ void rpass(float st[32], float c, float s) {
#pragma unroll
    for (int k = 0; k < 16; ++k) {
        const int n0 = ((k >> BIT) << (BIT + 1)) | (k & ((1 << BIT) - 1));
        const int n1 = n0 | (1 << BIT);
        float a = st[n0], b = st[n1];
        st[n0] = c * a - s * b;
        st[n1] = s * a + c * b;
    }
}

__global__ __launch_bounds__(BLOCK, 4)
void quantum_kernel(const float* __restrict__ x,   // [B,14]
                    const float* __restrict__ w,   // [2,14]
                    float* __restrict__ out)       // [B,14]
{
    alignas(16) __shared__ float lds[BLOCK * SCHUNK];   // 73728 B
    __shared__ float2 cs0[Q], cs1[Q];
    __shared__ float red[16 * 12];

    const int b = blockIdx.x;
    const int tid = threadIdx.x;
    const int lane = tid & 63;

    if (tid < Q) {
        float a0 = 0.5f * (x[b * Q + tid] + w[tid]);   // RY(x)·RY(w0) merged
        cs0[tid] = make_float2(cosf(a0), sinf(a0));
        float a1 = 0.5f * w[Q + tid];
        cs1[tid] = make_float2(cosf(a1), sinf(a1));
    }
    __syncthreads();

    // ---- Fill (phase A). tid = m[8:0], local r = m[13:9].
    // wire i uses g bit (13-i), g_b = m_b ^ m_{b+1}; g bits 0..7 thread-uniform.
    float H = 1.0f;
#pragma unroll
    for (int j = 0; j <= 7; ++j) {
        int gj = ((tid >> (j + 1)) ^ (tid >> j)) & 1;
        float2 f = cs0[13 - j];
        H *= gj ? f.y : f.x;
    }
    const int t8 = (tid >> 8) & 1;                 // wire5: g8 = t8 ^ r0
    float2 f5 = cs0[5];
    float F5_0 = t8 ? f5.y : f5.x;
    float F5_1 = t8 ? f5.x : f5.y;
    float2 f4 = cs0[4], f3 = cs0[3], f2 = cs0[2], f1 = cs0[1], f0 = cs0[0];

    float st[32];
    {
        float t1[2], t2[4], t3[8], t4[16];
        t1[0] = H * F5_0;  t1[1] = H * F5_1;
#pragma unroll
        for (int r = 0; r < 4; ++r) {              // wire4: g9 = r0^r1
            int g = ((r >> 1) ^ r) & 1;
            t2[r] = t1[r & 1] * (g ? f4.y : f4.x);
        }
#pragma unroll
        for (int r = 0; r < 8; ++r) {              // wire3: g10 = r1^r2
            int g = ((r >> 2) ^ (r >> 1)) & 1;
            t3[r] = t2[r & 3] * (g ? f3.y : f3.x);
        }
#pragma unroll
        for (int r = 0; r < 16; ++r) {             // wire2: g11 = r2^r3
            int g = ((r >> 3) ^ (r >> 2)) & 1;
            t4[r] = t3[r & 7] * (g ? f2.y : f2.x);
        }
        float FF00 = f0.x * f1.x;                  // wire1: g12=r3^r4; wire0: g13=r4
        float FF01 = f0.x * f1.y;
        float FF10 = f0.y * f1.y;
        float FF11 = f0.y * f1.x;
#pragma unroll
        for (int r = 0; r < 32; ++r) {
            int r4b = (r >> 4) & 1, r3b = (r >> 3) & 1;
            float FFv = r4b ? (r3b ? FF11 : FF10) : (r3b ? FF01 : FF00);
            st[r] = t4[r & 15] * FFv;
        }
    }

    // ---- Phase A passes: wires 0..4 on r bits 4..0
    { float2 cs = cs1[0]; rpass<4>(st, cs.x, cs.y); }
    { float2 cs = cs1[1]; rpass<3>(st, cs.x, cs.y); }
    { float2 cs = cs1[2]; rpass<2>(st, cs.x, cs.y); }
    { float2 cs = cs1[3]; rpass<1>(st, cs.x, cs.y); }
    { float2 cs = cs1[4]; rpass<0>(st, cs.x, cs.y); }

    // ---- Transpose: element r of thread t -> chunk (r<<4)|(t&15), slot t>>4.
    {
        const int base = (tid & 15) * SCHUNK + (tid >> 4);
#pragma unroll
        for (int r = 0; r < 32; ++r)
            lds[base + (r << 4) * SCHUNK] = st[r];
    }
    __syncthreads();
    {
        const float4* rp = (const float4*)&lds[tid * SCHUNK];  // 144 B stride, aligned
#pragma unroll
        for (int u = 0; u < 8; ++u) {
            float4 q = rp[u];
            st[4 * u] = q.x; st[4 * u + 1] = q.y;
            st[4 * u + 2] = q.z; st[4 * u + 3] = q.w;
        }
    }
    // now tid = (m[13:9]<<4)|m[3:0], local u = m[8:4]

    // ---- Phase B passes: wires 5..9 on u bits 4..0
    { float2 cs = cs1[5]; rpass<4>(st, cs.x, cs.y); }
    { float2 cs = cs1[6]; rpass<3>(st, cs.x, cs.y); }
    { float2 cs = cs1[7]; rpass<2>(st, cs.x, cs.y); }
    { float2 cs = cs1[8]; rpass<1>(st, cs.x, cs.y); }
    { float2 cs = cs1[9]; rpass<0>(st, cs.x, cs.y); }

    // ---- Wire 10: xor8 = DPP row_ror:8 (exact xor partner within 16-lane row)
    {
        float2 cs = cs1[10];
        float sg = (lane & 8) ? cs.y : -cs.y;
#pragma unroll
        for (int u = 0; u < 32; ++u) {
            float pv = dppf<0x128>(st[u]);
            st[u] = fmaf(cs.x, st[u], sg * pv);
        }
    }
    // ---- Wire 11: xor4 via ds_swizzle (immediate pattern)
    {
        float2 cs = cs1[11];
        float sg = (lane & 4) ? cs.y : -cs.y;
#pragma unroll
        for (int u = 0; u < 32; ++u) {
            float pv = swzf<0x101F>(st[u]);
            st[u] = fmaf(cs.x, st[u], sg * pv);
        }
    }
    // ---- Wire 12: xor2 = DPP quad_perm [2,3,0,1]
    {
        float2 cs = cs1[12];
        float sg = (lane & 2) ? cs.y : -cs.y;
#pragma unroll
        for (int u = 0; u < 32; ++u) {
            float pv = dppf<0x4E>(st[u]);
            st[u] = fmaf(cs.x, st[u], sg * pv);
        }
    }
    // ---- Wire 13: xor1 = DPP quad_perm [1,0,3,2]
    {
        float2 cs = cs1[13];
        float sg = (lane & 1) ? cs.y : -cs.y;
#pragma unroll
        for (int u = 0; u < 32; ++u) {
            float pv = dppf<0xB1>(st[u]);
            st[u] = fmaf(cs.x, st[u], sg * pv);
        }
    }

    // ---- Measurement: 6 accumulators, compile-time signs on u bits (sign-folded fma)
    float acc0 = 0.f, acc1 = 0.f, acc2 = 0.f, acc3 = 0.f, acc4 = 0.f, acc5 = 0.f;
#pragma unroll
    for (int u = 0; u < 32; ++u) {
        float v = st[u];
        acc0 = fmaf(v, v, acc0);
        acc1 = (__builtin_popcount(u >> 4) & 1) ? fmaf(v, -v, acc1) : fmaf(v, v, acc1);
        acc2 = (__builtin_popcount(u >> 3) & 1) ? fmaf(v, -v, acc2) : fmaf(v, v, acc2);
        acc3 = (__builtin_popcount(u >> 2) & 1) ? fmaf(v, -v, acc3) : fmaf(v, v, acc3);
        acc4 = (__builtin_popcount(u >> 1) & 1) ? fmaf(v, -v, acc4) : fmaf(v, v, acc4);
        acc5 = (__builtin_popcount(u) & 1)      ? fmaf(v, -v, acc5) : fmaf(v, v, acc5);
    }

    // ---- Reduction. tid bits: 8..4 = m[13:9], 3..0 = m[3:0].
    // Partial groups h = tid>>5 = m[13:10] (16 per block); within a 32-half,
    // lane bits 4..0 = m9, m3..m0 -> signs pre-multiplied before sum32.
    const int ll = lane & 31;
    const float g4 = ((ll >> 4) & 1) ? -1.f : 1.f;                    // m9
    const float g3 = (__builtin_popcount(ll >> 3) & 1) ? -1.f : 1.f;  // m9,m3
    const float g2 = (__builtin_popcount(ll >> 2) & 1) ? -1.f : 1.f;  // m9,m3,m2
    const float g1 = (__builtin_popcount(ll >> 1) & 1) ? -1.f : 1.f;  // +m1
    const float g0 = (__builtin_popcount(ll) & 1) ? -1.f : 1.f;       // +m0

    float R0  = sum32(acc0);        // outs 0..3 (signs live on h)
    float R1  = sum32(g4 * acc0);   // out 4
    float R2  = sum32(g4 * acc1);   // out 5
    float R3  = sum32(g4 * acc2);   // out 6
    float R4  = sum32(g4 * acc3);   // out 7
    float R5  = sum32(g4 * acc4);   // out 8
    float R6  = sum32(g4 * acc5);   // out 9
    float R7  = sum32(g3 * acc5);   // out 10
    float R8  = sum32(g2 * acc5);   // out 11
    float R9  = sum32(g1 * acc5);   // out 12
    float R10 = sum32(g0 * acc5);   // out 13

    if (ll == 0) {
        float* rp = &red[(tid >> 5) * 12];
        rp[0] = R0;  rp[1] = R1;  rp[2] = R2;  rp[3] = R3;
        rp[4] = R4;  rp[5] = R5;  rp[6] = R6;  rp[7] = R7;
        rp[8] = R8;  rp[9] = R9;  rp[10] = R10;
    }
    __syncthreads();

    // Tail: out_i = sum_h sign_i(h) * red[h][k(i)], h = m[13:10].
    if (tid < Q) {
        const int k = (tid <= 3) ? 0 : (tid - 3);
        const int sh = (tid == 0) ? 3 : (tid == 1) ? 2 : (tid == 2) ? 1 : 0;
        float s = 0.f;
#pragma unroll
        for (int h = 0; h < 16; ++h) {
            float r = red[h * 12 + k];
            s += (__builtin_popcount(h >> sh) & 1) ? -r : r;
        }
        out[b * Q + tid] = s;
    }
}

extern "C" void kernel_launch(void* const* d_in, const int* in_sizes, int n_in,
                              void* d_out, int out_size, void* d_ws, size_t ws_size,
                              hipStream_t stream) {
    const float* x = (const float*)d_in[0];
    const float* w = (const float*)d_in[1];
    float* out = (float*)d_out;
    const int B = in_sizes[0] / Q;   // 512
    quantum_kernel<<<dim3(B), dim3(BLOCK), 0, stream>>>(x, w, out);
}

// Round 5
// 63.864 us; speedup vs baseline: 1.0895x; 1.0079x over previous
//
#include <hip/hip_runtime.h>
#include <math.h>

// QuantumLayer B=512, Q=14. State 2^14 fp32 in registers: 32/thread x 512 threads,
// held as float2 A[16] to enable packed v_pk_fma_f32 (2 FP32 FMA / instruction).
//
// m = state index, bit 13 = wire 0 (MSB).
// Phase A: local r = m[13:9] (A[16], r bit0 = m9 = float2 component), tid = m[8:0]
//   -> wires 0..3 = float2 butterflies on j bits 3..0; wire 4 = intra-float2.
// LDS transpose (chunk stride 36 floats; scatter b32 writes 2-way/bank = free,
//   reads ds_read_b128) to Phase B: local u = m[8:4], tid' = (m[13:9]<<4)|m[3:0]
//   -> wires 5..8 float2 butterflies; wire 9 intra-float2; wires 10..13 on lane
//   bits 3..0: xor8 = DPP row_ror:8, xor4 = ds_swizzle, xor2/xor1 = DPP quad_perm.
// Fill: RY(x)+RY(w0) merged (same-wire RYs compose), pushed through CNOT chain #1
//   (g = m ^ (m>>1)), built as a product tree. Chain #2 folded into measurement
//   as prefix-parity signs (compile-time per element).
// Reduction: 11 shared 32-lane sums (4 DPP row_ror adds + 1 xor16 swizzle);
//   m[13:10] signs resolved via 16 partial groups in LDS.

#define Q 14
#define BLOCK 512
#define SCHUNK 36   // 32 data + 4 pad floats; 144 B chunk, 16B-aligned

template<int CTRL>
__device__ __forceinline__ float dppf(float v) {
    return __int_as_float(__builtin_amdgcn_update_dpp(
        0, __float_as_int(v), CTRL, 0xF, 0xF, true));
}
template<int OFF>
__device__ __forceinline__ float swzf(float v) {
    return __int_as_float(__builtin_amdgcn_ds_swizzle(__float_as_int(v), OFF));
}

// all-reduce sum over a 32-lane half: DPP rotates within 16-rows, then xor16.
__device__ __forceinline__ float sum32(float v) {
    v += dppf<0x121>(v);   // row_ror:1
    v += dppf<0x122>(v);   // row_ror:2
    v += dppf<0x124>(v);   // row_ror:4
    v += dppf<0x128>(v);   // row_ror:8
    v += swzf<0x401F>(v);  // xor16
    return v;
}

// Butterfly on j-bit B2 over float2 array (element bit B2+1): 8 packed pairs.
template<int B2>
__device__ __forceinline__ void rpass2(float2 A[16], float c, float s) {
#pragma unroll
    for (int t = 0; t < 8; ++t) {
        const int j0 = ((t >> B2) << (B2 + 1)) | (t & ((1 << B2) - 1));
        const int j1 = j0 | (1 << B2);
        float2 a = A[j0], b = A[j1];
        A[j0] = make_float2(c * a.x - s * b.x, c * a.y - s * b.y);  // pk ops
        A[j1] = make_float2(s * a.x + c * b.x, s * a.y + c * b.y);
    }
}

// Butterfly on element bit 0 (intra-float2).
__device__ __forceinline__ void rpass_intra(float2 A[16], float c, float s) {
#pragma unroll
    for (int j = 0; j < 16; ++j) {
        float2 a = A[j];
        A[j] = make_float2(c * a.x - s * a.y, s * a.x + c * a.y);
    }
}

__global__ __launch_bounds__(BLOCK, 4)
void quantum_kernel(const float* __restrict__ x,   // [B,14]
                    const float* __restrict__ w,   // [2,14]
                    float* __restrict__ out)       // [B,14]
{
    alignas(16) __shared__ float lds[BLOCK * SCHUNK];   // 73728 B
    __shared__ float2 cs0[Q], cs1[Q];
    __shared__ float red[16 * 12];

    const int b = blockIdx.x;
    const int tid = threadIdx.x;
    const int lane = tid & 63;

    if (tid < Q) {
        float a0 = 0.5f * (x[b * Q + tid] + w[tid]);   // RY(x)·RY(w0) merged
        cs0[tid] = make_float2(cosf(a0), sinf(a0));
        float a1 = 0.5f * w[Q + tid];
        cs1[tid] = make_float2(cosf(a1), sinf(a1));
    }
    __syncthreads();

    // ---- Fill (phase A). tid = m[8:0], element index r = m[13:9].
    // wire i uses g bit (13-i), g_b = m_b ^ m_{b+1}; g bits 0..7 thread-uniform.
    float H = 1.0f;
#pragma unroll
    for (int j = 0; j <= 7; ++j) {
        int gj = ((tid >> (j + 1)) ^ (tid >> j)) & 1;
        float2 f = cs0[13 - j];
        H *= gj ? f.y : f.x;
    }
    const int t8 = (tid >> 8) & 1;                 // wire5: g8 = t8 ^ r0
    float2 f5 = cs0[5];
    float F5_0 = t8 ? f5.y : f5.x;
    float F5_1 = t8 ? f5.x : f5.y;
    float2 f4 = cs0[4], f3 = cs0[3], f2 = cs0[2], f1 = cs0[1], f0 = cs0[0];

    float2 A[16];   // A[j] = elements r=2j (.x), r=2j+1 (.y); r bit0 = m9
    {
        float t1[2], t2[4], t3[8], t4[16];
        t1[0] = H * F5_0;  t1[1] = H * F5_1;
#pragma unroll
        for (int r = 0; r < 4; ++r) {              // wire4: g9 = r0^r1
            int g = ((r >> 1) ^ r) & 1;
            t2[r] = t1[r & 1] * (g ? f4.y : f4.x);
        }
#pragma unroll
        for (int r = 0; r < 8; ++r) {              // wire3: g10 = r1^r2
            int g = ((r >> 2) ^ (r >> 1)) & 1;
            t3[r] = t2[r & 3] * (g ? f3.y : f3.x);
        }
#pragma unroll
        for (int r = 0; r < 16; ++r) {             // wire2: g11 = r2^r3
            int g = ((r >> 3) ^ (r >> 2)) & 1;
            t4[r] = t3[r & 7] * (g ? f2.y : f2.x);
        }
        float FF00 = f0.x * f1.x;                  // wire1: g12=r3^r4; wire0: g13=r4
        float FF01 = f0.x * f1.y;
        float FF10 = f0.y * f1.y;
        float FF11 = f0.y * f1.x;
#pragma unroll
        for (int j = 0; j < 16; ++j) {             // pack final level: r=2j, 2j+1
            int r0 = 2 * j, r1 = 2 * j + 1;
            int a4 = (r0 >> 4) & 1, a3 = (r0 >> 3) & 1;
            int b4 = (r1 >> 4) & 1, b3 = (r1 >> 3) & 1;
            float Fa = a4 ? (a3 ? FF11 : FF10) : (a3 ? FF01 : FF00);
            float Fb = b4 ? (b3 ? FF11 : FF10) : (b3 ? FF01 : FF00);
            A[j] = make_float2(t4[r0 & 15] * Fa, t4[r1 & 15] * Fb);  // pk_mul
        }
    }

    // ---- Phase A passes: wires 0..3 on j bits 3..0 (packed), wire 4 intra.
    { float2 cs = cs1[0]; rpass2<3>(A, cs.x, cs.y); }
    { float2 cs = cs1[1]; rpass2<2>(A, cs.x, cs.y); }
    { float2 cs = cs1[2]; rpass2<1>(A, cs.x, cs.y); }
    { float2 cs = cs1[3]; rpass2<0>(A, cs.x, cs.y); }
    { float2 cs = cs1[4]; rpass_intra(A, cs.x, cs.y); }

    // ---- Transpose: element r of thread t -> chunk (r<<4)|(t&15), slot t>>4.
    {
        const int base = (tid & 15) * SCHUNK + (tid >> 4);
#pragma unroll
        for (int j = 0; j < 16; ++j) {
            lds[base + ((2 * j) << 4) * SCHUNK]     = A[j].x;
            lds[base + ((2 * j + 1) << 4) * SCHUNK] = A[j].y;
        }
    }
    __syncthreads();
    {
        const float4* rp = (const float4*)&lds[tid * SCHUNK];  // 144 B stride, aligned
#pragma unroll
        for (int k = 0; k < 8; ++k) {
            float4 q = rp[k];
            A[2 * k]     = make_float2(q.x, q.y);
            A[2 * k + 1] = make_float2(q.z, q.w);
        }
    }
    // now tid = (m[13:9]<<4)|m[3:0], element index u = m[8:4], u bit0 = m4 = component

    // ---- Phase B passes: wires 5..8 on j bits 3..0 (packed), wire 9 intra.
    { float2 cs = cs1[5]; rpass2<3>(A, cs.x, cs.y); }
    { float2 cs = cs1[6]; rpass2<2>(A, cs.x, cs.y); }
    { float2 cs = cs1[7]; rpass2<1>(A, cs.x, cs.y); }
    { float2 cs = cs1[8]; rpass2<0>(A, cs.x, cs.y); }
    { float2 cs = cs1[9]; rpass_intra(A, cs.x, cs.y); }

    // ---- Wire 10: xor8 = DPP row_ror:8 (lane bit 3)
    {
        float2 cs = cs1[10];
        float sg = (lane & 8) ? cs.y : -cs.y;
#pragma unroll
        for (int j = 0; j < 16; ++j) {
            float px = dppf<0x128>(A[j].x);
            float py = dppf<0x128>(A[j].y);
            A[j] = make_float2(cs.x * A[j].x + sg * px,
                               cs.x * A[j].y + sg * py);
        }
    }
    // ---- Wire 11: xor4 via ds_swizzle (lane bit 2)
    {
        float2 cs = cs1[11];
        float sg = (lane & 4) ? cs.y : -cs.y;
#pragma unroll
        for (int j = 0; j < 16; ++j) {
            float px = swzf<0x101F>(A[j].x);
            float py = swzf<0x101F>(A[j].y);
            A[j] = make_float2(cs.x * A[j].x + sg * px,
                               cs.x * A[j].y + sg * py);
        }
    }
    // ---- Wire 12: xor2 = DPP quad_perm [2,3,0,1] (lane bit 1)
    {
        float2 cs = cs1[12];
        float sg = (lane & 2) ? cs.y : -cs.y;
#pragma unroll
        for (int j = 0; j < 16; ++j) {
            float px = dppf<0x4E>(A[j].x);
            float py = dppf<0x4E>(A[j].y);
            A[j] = make_float2(cs.x * A[j].x + sg * px,
                               cs.x * A[j].y + sg * py);
        }
    }
    // ---- Wire 13: xor1 = DPP quad_perm [1,0,3,2] (lane bit 0)
    {
        float2 cs = cs1[13];
        float sg = (lane & 1) ? cs.y : -cs.y;
#pragma unroll
        for (int j = 0; j < 16; ++j) {
            float px = dppf<0xB1>(A[j].x);
            float py = dppf<0xB1>(A[j].y);
            A[j] = make_float2(cs.x * A[j].x + sg * px,
                               cs.x * A[j].y + sg * py);
        }
    }

    // ---- Measurement (packed): u = 2j + e. acc_k sign = parity(u >> (5-k)).
    // k=1..4: sign uniform per j; k=5: components get opposite signs.
    float2 acV0 = make_float2(0.f, 0.f), acV1 = acV0, acV2 = acV0,
           acV3 = acV0, acV4 = acV0, acV5 = acV0;
#pragma unroll
    for (int j = 0; j < 16; ++j) {
        float2 v = A[j];
        float2 p = make_float2(v.x * v.x, v.y * v.y);          // pk_mul
        acV0 = make_float2(acV0.x + p.x, acV0.y + p.y);        // pk_add
        const float s1 = ((j >> 3) & 1) ? -1.f : 1.f;                       // u>>4
        const float s2 = (__builtin_popcount(j >> 2) & 1) ? -1.f : 1.f;     // u>>3
        const float s3 = (__builtin_popcount(j >> 1) & 1) ? -1.f : 1.f;     // u>>2
        const float s4 = (__builtin_popcount(j) & 1) ? -1.f : 1.f;          // u>>1
        acV1 = make_float2(acV1.x + s1 * p.x, acV1.y + s1 * p.y);
        acV2 = make_float2(acV2.x + s2 * p.x, acV2.y + s2 * p.y);
        acV3 = make_float2(acV3.x + s3 * p.x, acV3.y + s3 * p.y);
        acV4 = make_float2(acV4.x + s4 * p.x, acV4.y + s4 * p.y);
        acV5 = make_float2(acV5.x + s4 * p.x, acV5.y - s4 * p.y);           // parity(u)
    }
    float acc0 = acV0.x + acV0.y;
    float acc1 = acV1.x + acV1.y;
    float acc2 = acV2.x + acV2.y;
    float acc3 = acV3.x + acV3.y;
    float acc4 = acV4.x + acV4.y;
    float acc5 = acV5.x + acV5.y;

    // ---- Reduction. tid bits: 8..4 = m[13:9], 3..0 = m[3:0].
    // Partial groups h = tid>>5 = m[13:10]; within a 32-half, lane bits 4..0 =
    // m9, m3..m0 -> signs pre-multiplied before sum32.
    const int ll = lane & 31;
    const float g4 = ((ll >> 4) & 1) ? -1.f : 1.f;                    // m9
    const float g3 = (__builtin_popcount(ll >> 3) & 1) ? -1.f : 1.f;  // m9,m3
    const float g2 = (__builtin_popcount(ll >> 2) & 1) ? -1.f : 1.f;
    const float g1 = (__builtin_popcount(ll >> 1) & 1) ? -1.f : 1.f;
    const float g0 = (__builtin_popcount(ll) & 1) ? -1.f : 1.f;

    float R0  = sum32(acc0);        // outs 0..3 (signs live on h)
    float R1  = sum32(g4 * acc0);   // out 4
    float R2  = sum32(g4 * acc1);   // out 5
    float R3  = sum32(g4 * acc2);   // out 6
    float R4  = sum32(g4 * acc3);   // out 7
    float R5  = sum32(g4 * acc4);   // out 8
    float R6  = sum32(g4 * acc5);   // out 9
    float R7  = sum32(g3 * acc5);   // out 10
    float R8  = sum32(g2 * acc5);   // out 11
    float R9  = sum32(g1 * acc5);   // out 12
    float R10 = sum32(g0 * acc5);   // out 13

    if (ll == 0) {
        float* rp = &red[(tid >> 5) * 12];
        rp[0] = R0;  rp[1] = R1;  rp[2] = R2;  rp[3] = R3;
        rp[4] = R4;  rp[5] = R5;  rp[6] = R6;  rp[7] = R7;
        rp[8] = R8;  rp[9] = R9;  rp[10] = R10;
    }
    __syncthreads();

    // Tail: out_i = sum_h sign_i(h) * red[h][k(i)], h = m[13:10].
    if (tid < Q) {
        const int k = (tid <= 3) ? 0 : (tid - 3);
        const int sh = (tid == 0) ? 3 : (tid == 1) ? 2 : (tid == 2) ? 1 : 0;
        float s = 0.f;
#pragma unroll
        for (int h = 0; h < 16; ++h) {
            float r = red[h * 12 + k];
            s += (__builtin_popcount(h >> sh) & 1) ? -r : r;
        }
        out[b * Q + tid] = s;
    }
}

extern "C" void kernel_launch(void* const* d_in, const int* in_sizes, int n_in,
                              void* d_out, int out_size, void* d_ws, size_t ws_size,
                              hipStream_t stream) {
    const float* x = (const float*)d_in[0];
    const float* w = (const float*)d_in[1];
    float* out = (float*)d_out;
    const int B = in_sizes[0] / Q;   // 512
    quantum_kernel<<<dim3(B), dim3(BLOCK), 0, stream>>>(x, w, out);
}